// Round 1
// baseline (100.857 us; speedup 1.0000x reference)
//
#include <hip/hip_runtime.h>

// Problem dims (fixed by reference): bs=4, L=512, H=768, C=48
#define H_DIM 768
#define C_DIM 48
#define NROWS 2048          // bs * L
#define TWO_H 1536

// ---------------------------------------------------------------------------
// Kernel 1: proj[half][row][c] = dot(hs[row,:], W[c, half*768 + :])
// grid = (24, 32), block = 256 (4 waves).
//   wave w of block bx handles c = bx*4 + w  (0..95; c<48 -> i-half, else j-half)
//   lane handles row = by*64 + lane          (0..2047)
// W row is wave-uniform -> scalar-cached; hs row per-lane (stride 3KB, L2/L3).
// ---------------------------------------------------------------------------
__global__ __launch_bounds__(256) void proj_kernel(const float* __restrict__ hs,
                                                   const float* __restrict__ W,
                                                   float* __restrict__ proj) {
    const int tid  = threadIdx.x;
    const int wave = tid >> 6;
    const int lane = tid & 63;

    int c = blockIdx.x * 4 + wave;                 // 0..95
    c = __builtin_amdgcn_readfirstlane(c);         // force wave-uniform
    const int half = (c >= C_DIM) ? 1 : 0;
    const int ci   = c - half * C_DIM;

    const int row = blockIdx.y * 64 + lane;        // 0..2047

    const float4* __restrict__ hrow =
        reinterpret_cast<const float4*>(hs + (size_t)row * H_DIM);
    const float4* __restrict__ wrow =
        reinterpret_cast<const float4*>(W + (size_t)ci * TWO_H + half * H_DIM);

    float acc = 0.f;
    #pragma unroll 8
    for (int k = 0; k < H_DIM / 4; ++k) {
        float4 h = hrow[k];
        float4 w = wrow[k];
        acc += h.x * w.x;
        acc += h.y * w.y;
        acc += h.z * w.z;
        acc += h.w * w.w;
    }

    proj[(size_t)half * (NROWS * C_DIM) + (size_t)row * C_DIM + ci] = acc;
}

// ---------------------------------------------------------------------------
// Kernel 2: out[b,i,j,c] = proj_i[b,i,c] + proj_j[b,j,c] + bias[c]
// grid = 2048 (one block per (b,i)), block = 256.
// In float4 units: out_slab[p] = projj_slab[p] + rowi[p % 12]
//   where slab = 512*48 floats = 6144 float4 (98 KB), fully linear.
// ---------------------------------------------------------------------------
__global__ __launch_bounds__(256) void bcast_kernel(const float* __restrict__ proj,
                                                    const float* __restrict__ bias,
                                                    float* __restrict__ out) {
    const int gi = blockIdx.x;          // global row index = b*512 + i
    const int b  = gi >> 9;             // batch

    __shared__ float4 rowi[C_DIM / 4];  // proj_i[b,i,:] + bias  (12 float4)

    const int t = threadIdx.x;
    if (t < C_DIM / 4) {
        float4 pi = reinterpret_cast<const float4*>(proj + (size_t)gi * C_DIM)[t];
        float4 bb = reinterpret_cast<const float4*>(bias)[t];
        pi.x += bb.x; pi.y += bb.y; pi.z += bb.z; pi.w += bb.w;
        rowi[t] = pi;
    }
    __syncthreads();

    const float4* __restrict__ pj =
        reinterpret_cast<const float4*>(proj + (size_t)(NROWS * C_DIM)
                                             + (size_t)b * 512 * C_DIM);
    float4* __restrict__ o =
        reinterpret_cast<float4*>(out) + (size_t)gi * (512 * C_DIM / 4);

    constexpr int SLAB_F4 = 512 * C_DIM / 4;   // 6144
    #pragma unroll
    for (int it = 0; it < SLAB_F4 / 256; ++it) {
        const int p  = it * 256 + t;
        const int c4 = p % 12;
        float4 v  = pj[p];
        float4 si = rowi[c4];
        v.x += si.x; v.y += si.y; v.z += si.z; v.w += si.w;
        o[p] = v;
    }
}

extern "C" void kernel_launch(void* const* d_in, const int* in_sizes, int n_in,
                              void* d_out, int out_size, void* d_ws, size_t ws_size,
                              hipStream_t stream) {
    const float* hs   = (const float*)d_in[0];   // (4, 512, 768) f32
    const float* W    = (const float*)d_in[1];   // (48, 1536)    f32
    const float* bias = (const float*)d_in[2];   // (48,)         f32
    float* out  = (float*)d_out;                 // (4,512,512,48) f32
    float* proj = (float*)d_ws;                  // 2 * 2048 * 48 floats = 786 KB

    // Kernel 1: compute both projections into workspace.
    proj_kernel<<<dim3(24, 32), 256, 0, stream>>>(hs, W, proj);

    // Kernel 2: broadcast-add, one block per (b, i).
    bcast_kernel<<<dim3(NROWS), 256, 0, stream>>>(proj, bias, out);
}